// Round 4
// baseline (5507.688 us; speedup 1.0000x reference)
//
#include <hip/hip_runtime.h>
#include <math.h>

#define HID   256
#define SEQ   512
#define BATCH 256
#define NPRED 64
#define NOUT  3
#define KCAT  515    // 3 (x_in) + 256 (ctx) + 256 (h)
#define KPAD  544    // padded to 17 k-tiles of 32 for MFMA
#define NKT   17     // k-tiles in gates GEMV
#define KPAD3 528    // round-3 fallback padding
#define NPAIR 264    // KPAD3/2
#define GATES 1024

typedef unsigned int u32;
typedef __attribute__((ext_vector_type(8))) short bf16x8;
typedef __attribute__((ext_vector_type(4))) float f32x4;

__device__ __forceinline__ float sigmoidf_(float x) { return 1.0f / (1.0f + __expf(-x)); }
__device__ __forceinline__ float tanh_(float x)     { return 1.0f - 2.0f / (__expf(2.0f * x) + 1.0f); }

__device__ __forceinline__ unsigned short f2bf(float f) {
    union { float f; u32 u; } c; c.f = f;
    u32 u = c.u + 0x7fffu + ((c.u >> 16) & 1u);
    return (unsigned short)(u >> 16);
}
__device__ __forceinline__ float bf2f(unsigned short s) {
    union { u32 x; float f; } c; c.x = (u32)s << 16; return c.f;
}
__device__ __forceinline__ u32 pack2(float a, float b) {
    return (u32)f2bf(a) | ((u32)f2bf(b) << 16);
}
__device__ __forceinline__ float bl(u32 u) { union { u32 x; float f; } c; c.x = u << 16;        return c.f; }
__device__ __forceinline__ float bh(u32 u) { union { u32 x; float f; } c; c.x = u & 0xffff0000u; return c.f; }
__device__ __forceinline__ bf16x8 asbf(uint4 u) { union { uint4 a; bf16x8 b; } c; c.a = u; return c.b; }

// ===========================================================================
// Shared prep: Ma = (Ua^T Wa) packed bf16 quads; v0 = Ua^T ba; bias_g.
// ===========================================================================
__global__ void prep_ma(const float* __restrict__ Wa, const float* __restrict__ Ua,
                        uint2* __restrict__ Ma4) {
    const int k4 = blockIdx.x, j = threadIdx.x;
    float acc[4] = {0.f, 0.f, 0.f, 0.f};
    for (int m = 0; m < HID; ++m) {
        const float ua = Ua[m * HID + j];
        #pragma unroll
        for (int q = 0; q < 4; ++q) acc[q] += Wa[m * HID + 4 * k4 + q] * ua;
    }
    Ma4[k4 * 256 + j] = make_uint2(pack2(acc[0], acc[1]), pack2(acc[2], acc[3]));
}

__global__ void prep_misc(const float* __restrict__ b_ih, const float* __restrict__ b_hh,
                          const float* __restrict__ ba, const float* __restrict__ Ua,
                          float* __restrict__ bias_g, float* __restrict__ v0) {
    const int t = threadIdx.x;
    if (t < GATES) bias_g[t] = b_ih[t] + b_hh[t];
    if (t < HID) {
        float acc = 0.f;
        for (int m = 0; m < HID; ++m) acc += ba[m] * Ua[m * HID + t];
        v0[t] = acc;
    }
}

// ===========================================================================
// MFMA-path preps: swizzle enc and Wcat into 16x16x32 fragment layouts.
// A-frag: lane L holds A[m=L&15][k=(L>>4)*8+j], j=0..7 (pairs packed in u32).
// B-frag: lane L holds B[n=L&15][k=(L>>4)*8+j].
// ===========================================================================
// enc_A[b][ts][tk][lane] : A[m=s in ts-tile][k=h in tk-tile]
__global__ void prep_encA(const float* __restrict__ enc, uint4* __restrict__ encA) {
    const int blk = blockIdx.x;          // b*32 + ts
    const int b = blk >> 5, ts = blk & 31;
    const int t = threadIdx.x;           // 512
    const int tk = t >> 6, L = t & 63;
    const int s = ts * 16 + (L & 15);
    const int h = tk * 32 + ((L >> 4) * 8);
    const float* p = enc + ((size_t)b * SEQ + s) * HID + h;
    const float4 f0 = *(const float4*)p;
    const float4 f1 = *(const float4*)(p + 4);
    encA[((size_t)(b * 32 + ts) * 8 + tk) * 64 + L] =
        make_uint4(pack2(f0.x, f0.y), pack2(f0.z, f0.w),
                   pack2(f1.x, f1.y), pack2(f1.z, f1.w));
}

// enc_B[b][tkh][tss][lane] : B[n=h in tkh-tile][k=s in tss-tile]
__global__ void prep_encB(const float* __restrict__ enc, uint4* __restrict__ encB) {
    const int blk = blockIdx.x;          // b*16 + tkh
    const int b = blk >> 4, tkh = blk & 15;
    const int t = threadIdx.x;           // 1024
    const int tss = t >> 6, L = t & 63;
    const int h = tkh * 16 + (L & 15);
    const int s0 = tss * 32 + ((L >> 4) * 8);
    float f[8];
    #pragma unroll
    for (int j = 0; j < 8; ++j)
        f[j] = enc[((size_t)b * SEQ + s0 + j) * HID + h];
    encB[((size_t)(b * 16 + tkh) * 16 + tss) * 64 + L] =
        make_uint4(pack2(f[0], f[1]), pack2(f[2], f[3]),
                   pack2(f[4], f[5]), pack2(f[6], f[7]));
}

// Wc_A[tk][tm][lane] : A[m=gate in tm-tile][k=kcat in tk-tile] (zero-pad k>=515)
__global__ void prep_wca(const float* __restrict__ W_ih, const float* __restrict__ W_hh,
                         uint4* __restrict__ WcA) {
    const int tk = blockIdx.x / 64, tm = blockIdx.x % 64;
    const int L = threadIdx.x;
    const int g = tm * 16 + (L & 15);
    const int k0 = tk * 32 + ((L >> 4) * 8);
    float f[8];
    #pragma unroll
    for (int j = 0; j < 8; ++j) {
        const int kk = k0 + j;
        f[j] = (kk < 259) ? W_ih[g * 259 + kk]
             : (kk < KCAT) ? W_hh[g * HID + (kk - 259)] : 0.f;
    }
    WcA[((size_t)tk * 64 + tm) * 64 + L] =
        make_uint4(pack2(f[0], f[1]), pack2(f[2], f[3]),
                   pack2(f[4], f[5]), pack2(f[6], f[7]));
}

// ===========================================================================
// MFMA decoder: one 1024-thread block (16 waves) per batch element.
// ===========================================================================
__global__ __launch_bounds__(1024)
void decoder_mfma(const uint4* __restrict__ encA,
                  const uint4* __restrict__ encB,
                  const float* __restrict__ h0, const float* __restrict__ c0,
                  const float* __restrict__ Wo, const float* __restrict__ bo,
                  const uint2* __restrict__ Ma4, const float* __restrict__ v0,
                  const uint4* __restrict__ WcA, const float* __restrict__ bias_g,
                  float* __restrict__ pred_out, float* __restrict__ hid_out,
                  float* __restrict__ attn_out)
{
    const int b  = blockIdx.x;
    const int t  = threadIdx.x;
    const int wv = t >> 6;        // 0..15
    const int L  = t & 63;
    const int j  = t & 255;
    const int ks = t >> 8;        // 0..3
    const int quad = L >> 4;      // 0..3
    const int col  = L & 15;

    __shared__ __align__(16) float s_h[HID], s_c[HID];
    __shared__ __align__(16) float s_part[4][HID];
    __shared__ __align__(16) u32   s_vq_hi[128], s_vq_lo[128];
    __shared__ __align__(16) float s_scores[SEQ];
    __shared__ __align__(16) u32   s_w_bf[256];
    __shared__ __align__(16) float s_xcat[KPAD];     // [x_in 0..2 | ctx 3..258 | h 259..514 | 0-pad]
    __shared__ __align__(16) u32   s_xh[KPAD / 2], s_xl[KPAD / 2];
    __shared__ __align__(16) float s_gates[GATES];
    __shared__ float s_red[4], s_red2[4];

    if (t < HID) {
        s_h[t] = h0[b * HID + t];
        s_c[t] = c0[b * HID + t];
        s_xcat[259 + t] = s_h[t];
        if (t < NOUT) s_xcat[t] = 0.0f;               // SOS
    }
    if (t < KPAD - KCAT) s_xcat[KCAT + t] = 0.0f;     // zero pad
    __syncthreads();

    const uint4* encA_b = encA + (size_t)b * 32 * 8 * 64;
    const uint4* encB_b = encB + (size_t)b * 16 * 16 * 64;
    float* attn_b0 = attn_out + (size_t)b * NPRED * SEQ;

    for (int n = 0; n < NPRED; ++n) {
        // ---- P1: vq partials on VALU (Ma bf16, fp32 acc), 4-way split-K ----
        {
            float acc = 0.0f;
            #pragma unroll 4
            for (int qq = 0; qq < 16; ++qq) {
                const int q = ks * 16 + qq;
                const uint2 u  = Ma4[q * 256 + j];
                const float4 h4 = *(const float4*)&s_h[4 * q];
                acc += bl(u.x) * h4.x + bh(u.x) * h4.y
                     + bl(u.y) * h4.z + bh(u.y) * h4.w;
            }
            s_part[ks][j] = acc;
        }
        __syncthreads();
        // ---- finalize vq pair + split into bf16 hi/lo ----
        if (t < 128) {
            const int i0 = 2 * t, i1 = 2 * t + 1;
            const float va = v0[i0] + s_part[0][i0] + s_part[1][i0] + s_part[2][i0] + s_part[3][i0];
            const float vb = v0[i1] + s_part[0][i1] + s_part[1][i1] + s_part[2][i1] + s_part[3][i1];
            const unsigned short ha = f2bf(va), hb = f2bf(vb);
            s_vq_hi[t] = (u32)ha | ((u32)hb << 16);
            s_vq_lo[t] = pack2(va - bf2f(ha), vb - bf2f(hb));
        }
        __syncthreads();

        // ---- Scores via MFMA: wave wv owns s-tiles ts0=2wv, 2wv+1 ----
        {
            const int ts0 = wv * 2;
            f32x4 a0 = {0.f, 0.f, 0.f, 0.f}, a1 = {0.f, 0.f, 0.f, 0.f};
            #pragma unroll 2
            for (int tk = 0; tk < 8; ++tk) {
                const int p0 = tk * 16 + quad * 4;
                const bf16x8 Bh = asbf(*(const uint4*)&s_vq_hi[p0]);
                const bf16x8 Bl = asbf(*(const uint4*)&s_vq_lo[p0]);
                const bf16x8 A0 = asbf(encA_b[((ts0    ) * 8 + tk) * 64 + L]);
                const bf16x8 A1 = asbf(encA_b[((ts0 + 1) * 8 + tk) * 64 + L]);
                a0 = __builtin_amdgcn_mfma_f32_16x16x32_bf16(A0, Bh, a0, 0, 0, 0);
                a0 = __builtin_amdgcn_mfma_f32_16x16x32_bf16(A0, Bl, a0, 0, 0, 0);
                a1 = __builtin_amdgcn_mfma_f32_16x16x32_bf16(A1, Bh, a1, 0, 0, 0);
                a1 = __builtin_amdgcn_mfma_f32_16x16x32_bf16(A1, Bl, a1, 0, 0, 0);
            }
            if (col == 0) {
                #pragma unroll
                for (int r = 0; r < 4; ++r) {
                    s_scores[ts0 * 16 + quad * 4 + r]       = a0[r];
                    s_scores[(ts0 + 1) * 16 + quad * 4 + r] = a1[r];
                }
            }
        }
        __syncthreads();

        // ---- exact softmax over 512 scores (t<256 owns a pair) ----
        float x0, x1, e0, e1;
        if (t < 256) {
            x0 = s_scores[2 * t]; x1 = s_scores[2 * t + 1];
            float mx = fmaxf(x0, x1);
            #pragma unroll
            for (int off = 32; off >= 1; off >>= 1) mx = fmaxf(mx, __shfl_xor(mx, off));
            if (L == 0) s_red[wv] = mx;
        }
        __syncthreads();
        if (t < 256) {
            const float M = fmaxf(fmaxf(s_red[0], s_red[1]), fmaxf(s_red[2], s_red[3]));
            e0 = __expf(x0 - M); e1 = __expf(x1 - M);
            float se = e0 + e1;
            #pragma unroll
            for (int off = 32; off >= 1; off >>= 1) se += __shfl_xor(se, off);
            if (L == 0) s_red2[wv] = se;
        }
        __syncthreads();
        if (t < 256) {
            const float invL = 1.0f / (s_red2[0] + s_red2[1] + s_red2[2] + s_red2[3]);
            const float w0 = e0 * invL, w1 = e1 * invL;
            ((float2*)(attn_b0 + (size_t)n * SEQ))[t] = make_float2(w0, w1);
            s_w_bf[t] = pack2(w0, w1);
        }
        __syncthreads();

        // ---- ctx via MFMA: wave wv owns h-tile wv; contract over 16 s-tiles ----
        {
            f32x4 ca = {0.f, 0.f, 0.f, 0.f};
            #pragma unroll 2
            for (int tss = 0; tss < 16; ++tss) {
                const int p0 = tss * 16 + quad * 4;
                const bf16x8 Aw = asbf(*(const uint4*)&s_w_bf[p0]);
                const bf16x8 Bv = asbf(encB_b[(wv * 16 + tss) * 64 + L]);
                ca = __builtin_amdgcn_mfma_f32_16x16x32_bf16(Aw, Bv, ca, 0, 0, 0);
            }
            if (L < 16) s_xcat[3 + wv * 16 + L] = ca[0];   // all m-rows equal
        }
        __syncthreads();

        // ---- pack xcat into bf16 hi/lo pairs ----
        if (t < KPAD / 2) {
            const float xa = s_xcat[2 * t], xb = s_xcat[2 * t + 1];
            const unsigned short ha = f2bf(xa), hb = f2bf(xb);
            s_xh[t] = (u32)ha | ((u32)hb << 16);
            s_xl[t] = pack2(xa - bf2f(ha), xb - bf2f(hb));
        }
        __syncthreads();

        // ---- Gates via MFMA: wave wv owns gate-tiles wv*4..wv*4+3 ----
        {
            f32x4 g0 = {0.f,0.f,0.f,0.f}, g1 = {0.f,0.f,0.f,0.f};
            f32x4 g2 = {0.f,0.f,0.f,0.f}, g3 = {0.f,0.f,0.f,0.f};
            for (int tk = 0; tk < NKT; ++tk) {
                const int p0 = tk * 16 + quad * 4;
                const bf16x8 Bh = asbf(*(const uint4*)&s_xh[p0]);
                const bf16x8 Bl = asbf(*(const uint4*)&s_xl[p0]);
                const uint4* Ab = WcA + ((size_t)tk * 64 + wv * 4) * 64 + L;
                const bf16x8 A0 = asbf(Ab[0]);
                const bf16x8 A1 = asbf(Ab[64]);
                const bf16x8 A2 = asbf(Ab[128]);
                const bf16x8 A3 = asbf(Ab[192]);
                g0 = __builtin_amdgcn_mfma_f32_16x16x32_bf16(A0, Bh, g0, 0, 0, 0);
                g0 = __builtin_amdgcn_mfma_f32_16x16x32_bf16(A0, Bl, g0, 0, 0, 0);
                g1 = __builtin_amdgcn_mfma_f32_16x16x32_bf16(A1, Bh, g1, 0, 0, 0);
                g1 = __builtin_amdgcn_mfma_f32_16x16x32_bf16(A1, Bl, g1, 0, 0, 0);
                g2 = __builtin_amdgcn_mfma_f32_16x16x32_bf16(A2, Bh, g2, 0, 0, 0);
                g2 = __builtin_amdgcn_mfma_f32_16x16x32_bf16(A2, Bl, g2, 0, 0, 0);
                g3 = __builtin_amdgcn_mfma_f32_16x16x32_bf16(A3, Bh, g3, 0, 0, 0);
                g3 = __builtin_amdgcn_mfma_f32_16x16x32_bf16(A3, Bl, g3, 0, 0, 0);
            }
            if (col == 0) {
                const int r0 = quad * 4;
                #pragma unroll
                for (int r = 0; r < 4; ++r) {
                    s_gates[(wv * 4    ) * 16 + r0 + r] = g0[r];
                    s_gates[(wv * 4 + 1) * 16 + r0 + r] = g1[r];
                    s_gates[(wv * 4 + 2) * 16 + r0 + r] = g2[r];
                    s_gates[(wv * 4 + 3) * 16 + r0 + r] = g3[r];
                }
            }
        }
        __syncthreads();

        // ---- LSTM pointwise (unit t); gate order i,f,g,o ----
        if (t < HID) {
            const float gi = bias_g[t]       + s_gates[t];
            const float gf = bias_g[256 + t] + s_gates[256 + t];
            const float gg = bias_g[512 + t] + s_gates[512 + t];
            const float go = bias_g[768 + t] + s_gates[768 + t];
            const float cn = sigmoidf_(gf) * s_c[t] + sigmoidf_(gi) * tanh_(gg);
            const float hn = sigmoidf_(go) * tanh_(cn);
            s_c[t] = cn;
            s_h[t] = hn;
            s_xcat[259 + t] = hn;
        }
        __syncthreads();

        // ---- pred[o] = Wo[o].h + bo[o]; feedback as next x_in ----
        if (wv < NOUT) {
            const float4 w4 = *(const float4*)&Wo[wv * HID + L * 4];
            const float4 h4 = *(const float4*)&s_h[L * 4];
            float p = w4.x * h4.x + w4.y * h4.y + w4.z * h4.z + w4.w * h4.w;
            #pragma unroll
            for (int off = 32; off >= 1; off >>= 1) p += __shfl_xor(p, off);
            if (L == 0) {
                p += bo[wv];
                s_xcat[wv] = p;
                pred_out[((size_t)b * NPRED + n) * NOUT + wv] = p;
            }
        }
        __syncthreads();
    }

    if (t < HID) hid_out[b * HID + t] = s_h[t];
}

// ===========================================================================
// Fallback path (round-3, proven): VALU decoder + its preps.
// ===========================================================================
__global__ void prep_wc(const float* __restrict__ W_ih, const float* __restrict__ W_hh,
                        uint4* __restrict__ Wc2) {
    const int p = blockIdx.x, j = threadIdx.x;
    const int k0 = 2 * p, k1 = 2 * p + 1;
    u32 comp[4];
    #pragma unroll
    for (int q = 0; q < 4; ++q) {
        const int g = 4 * j + q;
        float w0 = 0.f, w1 = 0.f;
        if (k0 < KCAT) w0 = (k0 < 259) ? W_ih[g * 259 + k0] : W_hh[g * HID + (k0 - 259)];
        if (k1 < KCAT) w1 = (k1 < 259) ? W_ih[g * 259 + k1] : W_hh[g * HID + (k1 - 259)];
        comp[q] = pack2(w0, w1);
    }
    Wc2[p * 256 + j] = make_uint4(comp[0], comp[1], comp[2], comp[3]);
}

__global__ void prep_enc(const float* __restrict__ enc, u32* __restrict__ enc_bf) {
    const int total = BATCH * SEQ * HID / 4;
    for (int i = blockIdx.x * blockDim.x + threadIdx.x; i < total;
         i += gridDim.x * blockDim.x) {
        const float4 f = ((const float4*)enc)[i];
        ((uint2*)enc_bf)[i] = make_uint2(pack2(f.x, f.y), pack2(f.z, f.w));
    }
}

template <bool ENCBF>
__global__ __launch_bounds__(1024)
void decoder_valu(const float* __restrict__ enc, const u32* __restrict__ enc_bf,
                  const float* __restrict__ h0, const float* __restrict__ c0,
                  const float* __restrict__ Wo, const float* __restrict__ bo,
                  const uint2* __restrict__ Ma4, const float* __restrict__ v0,
                  const uint4* __restrict__ Wc2, const float* __restrict__ bias_g,
                  float* __restrict__ pred_out, float* __restrict__ hid_out,
                  float* __restrict__ attn_out)
{
    const int b = blockIdx.x, t = threadIdx.x;
    const int wave = t >> 6, lane = t & 63, j = t & 255, ks = t >> 8;

    __shared__ __align__(16) float s_h[HID], s_c[HID], s_vq[HID];
    __shared__ __align__(16) float s_xcat[KPAD3];
    __shared__ __align__(16) float s_scores[SEQ];
    __shared__ __align__(16) float s_gp[4096];
    __shared__ __align__(16) float s_part[4][HID];
    __shared__ float s_wm[16], s_wl[16], s_M, s_invL;

    if (t < HID) {
        s_h[t] = h0[b * HID + t]; s_c[t] = c0[b * HID + t];
        s_xcat[259 + t] = s_h[t];
        if (t < NOUT) s_xcat[t] = 0.0f;
    }
    if (t < KPAD3 - KCAT) s_xcat[KCAT + t] = 0.0f;
    __syncthreads();

    const float* encb    = enc + (size_t)b * SEQ * HID;
    const u32*   encb_bf = ENCBF ? (enc_bf + (size_t)b * SEQ * (HID / 2)) : nullptr;

    for (int n = 0; n < NPRED; ++n) {
        {
            float acc = 0.0f;
            #pragma unroll 4
            for (int qq = 0; qq < 16; ++qq) {
                const int q = ks * 16 + qq;
                const uint2 u  = Ma4[q * 256 + j];
                const float4 h4 = *(const float4*)&s_h[4 * q];
                acc += bl(u.x) * h4.x + bh(u.x) * h4.y + bl(u.y) * h4.z + bh(u.y) * h4.w;
            }
            s_part[ks][j] = acc;
        }
        __syncthreads();
        if (t < HID)
            s_vq[t] = v0[t] + s_part[0][t] + s_part[1][t] + s_part[2][t] + s_part[3][t];
        __syncthreads();

        const float4 vq4 = *(const float4*)&s_vq[lane * 4];
        float m = -INFINITY, lsum = 0.0f;
        float4 cacc = {0.f, 0.f, 0.f, 0.f};
        for (int s = wave; s < SEQ; s += 16) {
            float e0, e1, e2, e3;
            if (ENCBF) {
                const uint2 u = *(const uint2*)(encb_bf + s * (HID / 2) + lane * 2);
                e0 = bl(u.x); e1 = bh(u.x); e2 = bl(u.y); e3 = bh(u.y);
            } else {
                const float4 e4 = *(const float4*)&encb[s * HID + lane * 4];
                e0 = e4.x; e1 = e4.y; e2 = e4.z; e3 = e4.w;
            }
            float p = e0 * vq4.x + e1 * vq4.y + e2 * vq4.z + e3 * vq4.w;
            #pragma unroll
            for (int off = 32; off >= 1; off >>= 1) p += __shfl_xor(p, off);
            const float score = p;
            if (lane == 0) s_scores[s] = score;
            const float mnew  = fmaxf(m, score);
            const float alpha = __expf(m - mnew);
            const float e     = __expf(score - mnew);
            lsum   = lsum * alpha + e;
            cacc.x = cacc.x * alpha + e0 * e; cacc.y = cacc.y * alpha + e1 * e;
            cacc.z = cacc.z * alpha + e2 * e; cacc.w = cacc.w * alpha + e3 * e;
            m = mnew;
        }
        *(float4*)&s_gp[wave * HID + lane * 4] = cacc;
        if (lane == 0) { s_wm[wave] = m; s_wl[wave] = lsum; }
        __syncthreads();

        if (t < HID) {
            float M = s_wm[0];
            #pragma unroll
            for (int w = 1; w < 16; ++w) M = fmaxf(M, s_wm[w]);
            float Lh = 0.0f, ctx = 0.0f;
            #pragma unroll
            for (int w = 0; w < 16; ++w) {
                const float a = __expf(s_wm[w] - M);
                Lh  += a * s_wl[w];
                ctx += a * s_gp[w * HID + t];
            }
            const float invL = 1.0f / Lh;
            s_xcat[3 + t] = ctx * invL;
            if (t == 0) { s_M = M; s_invL = invL; }
        }
        __syncthreads();

        if (t < SEQ)
            attn_out[((size_t)b * NPRED + n) * SEQ + t] = __expf(s_scores[t] - s_M) * s_invL;

        {
            float4 g4 = {0.f, 0.f, 0.f, 0.f};
            const int pbeg = ks * 66;
            #pragma unroll 2
            for (int pp = 0; pp < 66; ++pp) {
                const int p = pbeg + pp;
                const uint4  w  = Wc2[p * 256 + j];
                const float2 xk = *(const float2*)&s_xcat[2 * p];
                g4.x += xk.x * bl(w.x) + xk.y * bh(w.x);
                g4.y += xk.x * bl(w.y) + xk.y * bh(w.y);
                g4.z += xk.x * bl(w.z) + xk.y * bh(w.z);
                g4.w += xk.x * bl(w.w) + xk.y * bh(w.w);
            }
            *(float4*)&s_gp[ks * GATES + j * 4] = g4;
        }
        __syncthreads();

        if (t < HID) {
            float gv[4];
            #pragma unroll
            for (int q = 0; q < 4; ++q) {
                const int gi = q * HID + t;
                gv[q] = bias_g[gi] + s_gp[gi] + s_gp[GATES + gi]
                      + s_gp[2 * GATES + gi] + s_gp[3 * GATES + gi];
            }
            const float cn = sigmoidf_(gv[1]) * s_c[t] + sigmoidf_(gv[0]) * tanh_(gv[2]);
            const float hn = sigmoidf_(gv[3]) * tanh_(cn);
            s_c[t] = cn; s_h[t] = hn; s_xcat[259 + t] = hn;
        }
        __syncthreads();

        if (wave < NOUT) {
            const float4 w4 = *(const float4*)&Wo[wave * HID + lane * 4];
            const float4 h4 = *(const float4*)&s_h[lane * 4];
            float p = w4.x * h4.x + w4.y * h4.y + w4.z * h4.z + w4.w * h4.w;
            #pragma unroll
            for (int off = 32; off >= 1; off >>= 1) p += __shfl_xor(p, off);
            if (lane == 0) {
                p += bo[wave];
                s_xcat[wave] = p;
                pred_out[((size_t)b * NPRED + n) * NOUT + wave] = p;
            }
        }
        __syncthreads();
    }
    if (t < HID) hid_out[b * HID + t] = s_h[t];
}

// ===========================================================================
extern "C" void kernel_launch(void* const* d_in, const int* in_sizes, int n_in,
                              void* d_out, int out_size, void* d_ws, size_t ws_size,
                              hipStream_t stream) {
    const float* enc  = (const float*)d_in[0];
    const float* h0   = (const float*)d_in[1];
    const float* c0   = (const float*)d_in[2];
    const float* Wa   = (const float*)d_in[3];
    const float* ba   = (const float*)d_in[4];
    const float* Ua   = (const float*)d_in[5];
    // d_in[6] = bua: score contribution constant over s -> softmax-invariant, dropped
    const float* W_ih = (const float*)d_in[7];
    const float* W_hh = (const float*)d_in[8];
    const float* b_ih = (const float*)d_in[9];
    const float* b_hh = (const float*)d_in[10];
    const float* Wo   = (const float*)d_in[11];
    const float* bo   = (const float*)d_in[12];

    char* ws = (char*)d_ws;
    uint4* WcA    = (uint4*)ws;  ws += (size_t)NKT * 64 * 64 * 16;   // 1,114,112
    uint4* Wc2    = (uint4*)ws;  ws += (size_t)NPAIR * 256 * 16;     // 1,081,344
    uint2* Ma4    = (uint2*)ws;  ws += (size_t)64 * 256 * 8;         //   131,072
    float* v0     = (float*)ws;  ws += 256 * 4;
    float* bias_g = (float*)ws;  ws += GATES * 4;
    const size_t base = (size_t)(ws - (char*)d_ws);
    const size_t enc_half = (size_t)BATCH * SEQ * HID * 2;           // 67,108,864
    uint4* encA   = (uint4*)ws;
    uint4* encB   = (uint4*)(ws + enc_half);
    u32*   enc_bf = (u32*)ws;

    float* pred_out = (float*)d_out;
    float* hid_out  = pred_out + BATCH * NPRED * NOUT;
    float* attn_out = hid_out + BATCH * HID;

    prep_ma  <<<dim3(64), dim3(256),  0, stream>>>(Wa, Ua, Ma4);
    prep_misc<<<dim3(1),  dim3(1024), 0, stream>>>(b_ih, b_hh, ba, Ua, bias_g, v0);

    if (ws_size >= base + 2 * enc_half) {
        prep_wca <<<dim3(NKT * 64),  dim3(64),   0, stream>>>(W_ih, W_hh, WcA);
        prep_encA<<<dim3(BATCH * 32), dim3(512),  0, stream>>>(enc, encA);
        prep_encB<<<dim3(BATCH * 16), dim3(1024), 0, stream>>>(enc, encB);
        decoder_mfma<<<dim3(BATCH), dim3(1024), 0, stream>>>(
            encA, encB, h0, c0, Wo, bo, Ma4, v0, WcA, bias_g,
            pred_out, hid_out, attn_out);
    } else if (ws_size >= base + enc_half) {
        prep_wc <<<dim3(NPAIR), dim3(256), 0, stream>>>(W_ih, W_hh, Wc2);
        prep_enc<<<dim3(2048),  dim3(256), 0, stream>>>(enc, enc_bf);
        decoder_valu<true><<<dim3(BATCH), dim3(1024), 0, stream>>>(
            enc, enc_bf, h0, c0, Wo, bo, Ma4, v0, Wc2, bias_g,
            pred_out, hid_out, attn_out);
    } else {
        prep_wc<<<dim3(NPAIR), dim3(256), 0, stream>>>(W_ih, W_hh, Wc2);
        decoder_valu<false><<<dim3(BATCH), dim3(1024), 0, stream>>>(
            enc, nullptr, h0, c0, Wo, bo, Ma4, v0, Wc2, bias_g,
            pred_out, hid_out, attn_out);
    }
}